// Round 19
// baseline (628.470 us; speedup 1.0000x reference)
//
#include <hip/hip_runtime.h>
#include <math.h>

#define T_TOK 8192
#define HDIM 2048
#define IDIM 1024
#define NE 8

typedef __attribute__((ext_vector_type(8))) short short8;
typedef __attribute__((ext_vector_type(4))) float f32x4;
typedef unsigned short u16;

__device__ inline u16 f2bf(float f) {
  unsigned u = __builtin_bit_cast(unsigned, f);
  u += 0x7fffu + ((u >> 16) & 1);  // RNE
  return (u16)(u >> 16);
}
__device__ inline float bf2f(u16 u) {
  unsigned v = (unsigned)u << 16;
  return __builtin_bit_cast(float, v);
}

// async global->LDS, 16B/lane. LDS dest = wave-uniform base + lane*16.
__device__ inline void gl_lds(const u16* g, u16* l) {
  __builtin_amdgcn_global_load_lds((const __attribute__((address_space(1))) unsigned int*)g,
                                   (__attribute__((address_space(3))) unsigned int*)l, 16, 0, 0);
}

// bf16 LDS tiles [row][32] (64B rows); chunk swizzle applied on the GLOBAL
// source address (m173): position p holds global chunk p ^ ((row>>1)&3).
// Frag read of granule g: row*32 + 8*(g ^ ((row>>1)&3)) -> measured 0 conflicts.
__device__ inline int rswz(int row, int g) { return row * 32 + 8 * (g ^ ((row >> 1) & 3)); }

// ---------- ws layout ----------
// 0       meta: cnt[8] cursor[8] (u32)
// 256     slot_token u16[2T]  (32 KB)
// 33024   slot_w    f32[2T]   (64 KB)
// 98560   tok2slot  u16[2T]   (32 KB)   -> ends 131328
// 132096  xbf  bf16[T*H]      (33.5 MB)
// ACT     act  bf16[2T*I]     (33.5 MB)  (sel/wt stashed here pre-k4)
// WGT     wgT / wuT           (67 MB)    -> y bf16[2T*H] after k4 (exact fit)
// WDT     wdT                 (33.5 MB)  total 167,904,256 (proven R5)

// ---------------- K0T: FUSED router (blocks 0..2047) & transpose (2048..5119).
// Transpose arm REWORKED (R19): [64k][256n] tiles, reads fully coalesced
// (1KB/wave-row, sequential), LDS transpose, dst written in 128B full-line
// chunks (strided side moved to fire-and-forget writes). DRAM-locality fix.
__global__ __launch_bounds__(256) void k0t_fused(
    const float* __restrict__ x, const float* __restrict__ wgate, u16* __restrict__ xb,
    float* __restrict__ logits_out, char* __restrict__ sel, float* __restrict__ wt,
    unsigned* __restrict__ cnt, const float* __restrict__ wg, u16* __restrict__ wgT,
    const float* __restrict__ wu, u16* __restrict__ wuT, const float* __restrict__ wd,
    u16* __restrict__ wdT) {
  __shared__ __align__(16) unsigned char smem[36864];
  unsigned bid = blockIdx.x;
  int tid = threadIdx.x;
  if (bid < T_TOK / 4) {
    // ---- router + x->bf16 (wgate via LDS slab) ----
    float* slab = (float*)smem;  // [256][9] f32, 9216 B
    int wave = tid >> 6;
    int lane = tid & 63;
    int tok = bid * 4 + wave;
    float acc[NE];
#pragma unroll
    for (int e = 0; e < NE; ++e) acc[e] = 0.f;
    const float4* xr = (const float4*)(x + (size_t)tok * HDIM);
    u16* xbrow = xb + (size_t)tok * HDIM;
    for (int c = 0; c < HDIM / 256; ++c) {
      if (c) __syncthreads();  // prev iter's slab reads done
      {
        const float4* wsrc = (const float4*)(wgate + (size_t)c * 2048 + tid * 8);
        float4 w0 = wsrc[0];
        float4 w1 = wsrc[1];
        float* sr = slab + tid * 9;
        sr[0] = w0.x; sr[1] = w0.y; sr[2] = w0.z; sr[3] = w0.w;
        sr[4] = w1.x; sr[5] = w1.y; sr[6] = w1.z; sr[7] = w1.w;
      }
      __syncthreads();
      float4 xv = xr[c * 64 + lane];
      int h = (c * 64 + lane) * 4;
      ushort4 o = make_ushort4(f2bf(xv.x), f2bf(xv.y), f2bf(xv.z), f2bf(xv.w));
      *(ushort4*)(xbrow + h) = o;
      const float xs[4] = {xv.x, xv.y, xv.z, xv.w};
#pragma unroll
      for (int j = 0; j < 4; ++j) {
        const float* wrow = slab + (size_t)(4 * lane + j) * 9;
#pragma unroll
        for (int e = 0; e < NE; ++e) acc[e] += xs[j] * wrow[e];
      }
    }
#pragma unroll
    for (int e = 0; e < NE; ++e) {
      float v = acc[e];
#pragma unroll
      for (int off = 32; off; off >>= 1) v += __shfl_xor(v, off, 64);
      acc[e] = v;
    }
    if (lane == 0) {
      float m = acc[0];
#pragma unroll
      for (int e = 0; e < NE; ++e) {
        logits_out[(size_t)tok * NE + e] = acc[e];
        m = fmaxf(m, acc[e]);
      }
      float p[NE];
#pragma unroll
      for (int e = 0; e < NE; ++e) p[e] = expf(acc[e] - m);
      int b0 = 0;
      float v0 = p[0];
#pragma unroll
      for (int e = 1; e < NE; ++e)
        if (p[e] > v0) { v0 = p[e]; b0 = e; }
      int b1 = -1;
      float v1 = -1.f;
#pragma unroll
      for (int e = 0; e < NE; ++e)
        if (e != b0 && p[e] > v1) { v1 = p[e]; b1 = e; }
      float denom = v0 + v1;
      sel[tok * 2 + 0] = (char)b0;
      sel[tok * 2 + 1] = (char)b1;
      wt[tok * 2 + 0] = v0 / denom;
      wt[tok * 2 + 1] = v1 / denom;
      atomicAdd(&cnt[b0], 1u);
      atomicAdd(&cnt[b1], 1u);
    }
    if (bid == 0 && tid >= 8 && tid < 16) cnt[tid] = 0;  // cursor[8]
  } else {
    // ---- transpose+cvt: dst[n][k] = bf16(src[k][n]) ----
    // tile [64k][256n]; COALESCED row reads; 128B-chunk dst writes.
    typedef u16 (*lt_t)[72];
    lt_t t = (lt_t)smem;  // [256][72] u16 = 36,864 B (rows 144 B, 16B-aligned)
    unsigned tb = bid - T_TOK / 4;  // 0..3071
    unsigned mat = tb / 1024u;      // 0=wg 1=wu 2=wd
    unsigned rem = tb % 1024u;
    unsigned e = rem >> 7;          // /128
    unsigned tile = rem & 127u;
    int K = (mat == 2) ? IDIM : HDIM;
    int N = (mat == 2) ? HDIM : IDIM;
    const float* src = (mat == 0 ? wg : mat == 1 ? wu : wd) + (size_t)e * K * N;
    u16* dst = (mat == 0 ? wgT : mat == 1 ? wuT : wdT) + (size_t)e * K * N;
    int ntn = N >> 8;  // n-tiles of 256: 4 (wg/wu) or 8 (wd)
    int kb = (int)(tile / ntn) * 64;
    int nb = (int)(tile % ntn) * 256;

    int ro = tid >> 6;        // row within 4-row group
    int cl = (tid & 63) * 4;  // col
    float4 v[16];
#pragma unroll
    for (int i = 0; i < 16; ++i)
      v[i] = *(const float4*)(src + (size_t)(kb + 4 * i + ro) * N + nb + cl);
#pragma unroll
    for (int i = 0; i < 16; ++i) {
      int k = 4 * i + ro;
      t[cl + 0][k] = f2bf(v[i].x);
      t[cl + 1][k] = f2bf(v[i].y);
      t[cl + 2][k] = f2bf(v[i].z);
      t[cl + 3][k] = f2bf(v[i].w);
    }
    __syncthreads();
    {
      u16* drow = dst + (size_t)(nb + tid) * K + kb;  // 64 bf16 = 2 full lines
#pragma unroll
      for (int c = 0; c < 8; ++c) *(short8*)(drow + 8 * c) = *(const short8*)&t[tid][8 * c];
    }
  }
}

// ---------------- K3: slot assignment (local prefix) ----------------
__global__ __launch_bounds__(256) void k3_assign(const char* __restrict__ sel,
                                                 const float* __restrict__ wt,
                                                 const unsigned* __restrict__ cnt,
                                                 unsigned* __restrict__ cursor,
                                                 u16* __restrict__ slot_token,
                                                 float* __restrict__ slot_w,
                                                 u16* __restrict__ tok2slot) {
  unsigned offv[NE];
  unsigned s = 0;
#pragma unroll
  for (int e = 0; e < NE; ++e) {
    offv[e] = s;
    s += cnt[e];
  }
  int t = blockIdx.x * 256 + threadIdx.x;
#pragma unroll
  for (int k = 0; k < 2; ++k) {
    int e = sel[t * 2 + k];
    unsigned p = atomicAdd(&cursor[e], 1u);
    unsigned slot = offv[e] + p;
    slot_token[slot] = (u16)t;
    slot_w[slot] = wt[t * 2 + k];
    tok2slot[t * 2 + k] = (u16)slot;
  }
}

// Bijective XCD swizzle for 64x8x8 = 4096-block grids (8 XCDs, 512/XCD).
__device__ inline void xcd_decomp(int& bx, int& by, int& be) {
  unsigned bid = blockIdx.x + 64u * (blockIdx.y + 8u * blockIdx.z);
  unsigned swz = (bid & 7u) * 512u + (bid >> 3);
  bx = swz & 63u;
  unsigned rem = swz >> 6;
  by = rem & 7u;
  be = rem >> 3;
}

// local exclusive-prefix over cnt (8 uniform L2-hot loads)
__device__ inline unsigned prefix_base(const unsigned* cnt, int e) {
  unsigned b = 0;
#pragma unroll
  for (int i = 0; i < NE; ++i) b += (i < e) ? cnt[i] : 0u;
  return b;
}

// ---------------- K4: MFMA gate+up + silu -> bf16 act (R9/R13 structure) ----------------
__global__ __launch_bounds__(256, 2) void k4_gateup(
    const u16* __restrict__ xb, const u16* __restrict__ wgT, const u16* __restrict__ wuT,
    const u16* __restrict__ slot_token, const unsigned* __restrict__ cnt,
    u16* __restrict__ act) {
  int bx, by, e;
  xcd_decomp(bx, by, e);
  unsigned n = cnt[e];
  unsigned row0 = (unsigned)bx * 128;
  if (row0 >= n) return;
  unsigned base = prefix_base(cnt, e);
  int col0 = by * 128;

  __shared__ __align__(16) u16 As[3][128 * 32];  // 24 KB
  __shared__ __align__(16) u16 Bg[3][128 * 32];  // 24 KB
  __shared__ __align__(16) u16 Bu[3][128 * 32];  // 24 KB

  int tid = threadIdx.x;
  int w = tid >> 6, l = tid & 63;
  int wr = w >> 1, wc = w & 1;
  int lr = l & 15, g = l >> 4;

  const u16* asrc[2];
  int adst[2];
#pragma unroll
  for (int i = 0; i < 2; ++i) {
    int r = 32 * w + 16 * i + (l >> 2);
    unsigned grow = row0 + (unsigned)r;
    unsigned slot = base + (grow < n ? grow : 0);
    int chunk = (l & 3) ^ ((r >> 1) & 3);
    asrc[i] = xb + (size_t)slot_token[slot] * HDIM + 8 * chunk;
    adst[i] = (32 * w + 16 * i) * 32;
  }
  const u16* bgsrc[2];
  const u16* busrc[2];
  int bdst[2];
#pragma unroll
  for (int i = 0; i < 2; ++i) {
    int nn = 32 * w + 16 * i + (l >> 2);
    int chunk = (l & 3) ^ ((nn >> 1) & 3);
    size_t o = (size_t)e * HDIM * IDIM + (size_t)(col0 + nn) * HDIM + 8 * chunk;
    bgsrc[i] = wgT + o;
    busrc[i] = wuT + o;
    bdst[i] = (32 * w + 16 * i) * 32;
  }

  int afo[4], bfo[4];
#pragma unroll
  for (int mf = 0; mf < 4; ++mf) afo[mf] = rswz(wr * 64 + mf * 16 + lr, g);
#pragma unroll
  for (int nf = 0; nf < 4; ++nf) bfo[nf] = rswz(wc * 64 + nf * 16 + lr, g);

  f32x4 accg[4][4] = {};
  f32x4 accu[4][4] = {};

#define K4_STAGE(k0, buf)                           \
  do {                                              \
    gl_lds(asrc[0] + (k0), &As[buf][adst[0]]);      \
    gl_lds(asrc[1] + (k0), &As[buf][adst[1]]);      \
    gl_lds(bgsrc[0] + (k0), &Bg[buf][bdst[0]]);     \
    gl_lds(bgsrc[1] + (k0), &Bg[buf][bdst[1]]);     \
    gl_lds(busrc[0] + (k0), &Bu[buf][bdst[0]]);     \
    gl_lds(busrc[1] + (k0), &Bu[buf][bdst[1]]);     \
  } while (0)

  K4_STAGE(0, 0);
  K4_STAGE(32, 1);  // 12 loads in flight

  const int NK = HDIM / 32;
  int c = 0, sb = 2;
  for (int kt = 0; kt < NK; ++kt) {
    if (kt + 2 < NK) {
      K4_STAGE((kt + 2) * 32, sb);                       // 18 in flight
      asm volatile("s_waitcnt vmcnt(12)" ::: "memory");  // tile kt landed
    } else if (kt + 1 < NK) {
      asm volatile("s_waitcnt vmcnt(6)" ::: "memory");
    } else {
      asm volatile("s_waitcnt vmcnt(0)" ::: "memory");
    }
    __builtin_amdgcn_s_barrier();

    short8 af[4];
#pragma unroll
    for (int mf = 0; mf < 4; ++mf) af[mf] = *(const short8*)&As[c][afo[mf]];
#pragma unroll
    for (int nf = 0; nf < 4; ++nf) {
      short8 bgf = *(const short8*)&Bg[c][bfo[nf]];
      short8 buf = *(const short8*)&Bu[c][bfo[nf]];
#pragma unroll
      for (int mf = 0; mf < 4; ++mf) {
        accg[mf][nf] = __builtin_amdgcn_mfma_f32_16x16x32_bf16(af[mf], bgf, accg[mf][nf], 0, 0, 0);
        accu[mf][nf] = __builtin_amdgcn_mfma_f32_16x16x32_bf16(af[mf], buf, accu[mf][nf], 0, 0, 0);
      }
    }
    __builtin_amdgcn_s_barrier();
    c = (c == 2) ? 0 : c + 1;
    sb = (sb == 2) ? 0 : sb + 1;
  }
#undef K4_STAGE

  unsigned rows_left = n - row0;
#pragma unroll
  for (int mf = 0; mf < 4; ++mf)
#pragma unroll
    for (int nf = 0; nf < 4; ++nf)
#pragma unroll
      for (int j = 0; j < 4; ++j) {
        int rin = wr * 64 + mf * 16 + 4 * g + j;
        if ((unsigned)rin < rows_left) {
          size_t s = base + row0 + rin;
          int col = col0 + wc * 64 + nf * 16 + lr;
          float gg = accg[mf][nf][j];
          float uu = accu[mf][nf][j];
          float v = (gg / (1.f + expf(-gg))) * uu;
          act[s * IDIM + col] = f2bf(v);
        }
      }
}

// ---------------- K5: MFMA down -> bf16 y (R9/R13 structure) ----------------
__global__ __launch_bounds__(256, 2) void k5_down(
    const u16* __restrict__ act, const u16* __restrict__ wdT,
    const unsigned* __restrict__ cnt, u16* __restrict__ y) {
  int bx, by, e;
  xcd_decomp(bx, by, e);
  unsigned n = cnt[e];
  unsigned row0 = (unsigned)bx * 128;
  if (row0 >= n) return;
  unsigned base = prefix_base(cnt, e);
  int col0 = by * 256;

  __shared__ __align__(16) u16 As[3][128 * 32];  // 24 KB
  __shared__ __align__(16) u16 Bs[3][256 * 32];  // 48 KB

  int tid = threadIdx.x;
  int w = tid >> 6, l = tid & 63;
  int wr = w >> 1, wc = w & 1;
  int lr = l & 15, g = l >> 4;

  const u16* asrc[2];
  int adst[2];
#pragma unroll
  for (int i = 0; i < 2; ++i) {
    int r = 32 * w + 16 * i + (l >> 2);
    unsigned grow = row0 + (unsigned)r;
    unsigned slot = base + (grow < n ? grow : 0);
    int chunk = (l & 3) ^ ((r >> 1) & 3);
    asrc[i] = act + (size_t)slot * IDIM + 8 * chunk;
    adst[i] = (32 * w + 16 * i) * 32;
  }
  const u16* bsrc[4];
  int bdst[4];
#pragma unroll
  for (int i = 0; i < 4; ++i) {
    int nn = 64 * w + 16 * i + (l >> 2);
    int chunk = (l & 3) ^ ((nn >> 1) & 3);
    bsrc[i] = wdT + (size_t)e * IDIM * HDIM + (size_t)(col0 + nn) * IDIM + 8 * chunk;
    bdst[i] = (64 * w + 16 * i) * 32;
  }

  int afo[4], bfo[8];
#pragma unroll
  for (int mf = 0; mf < 4; ++mf) afo[mf] = rswz(wr * 64 + mf * 16 + lr, g);
#pragma unroll
  for (int nf = 0; nf < 8; ++nf) bfo[nf] = rswz(wc * 128 + nf * 16 + lr, g);

  f32x4 acc[4][8] = {};

#define K5_STAGE(k0, buf)                        \
  do {                                           \
    gl_lds(asrc[0] + (k0), &As[buf][adst[0]]);   \
    gl_lds(asrc[1] + (k0), &As[buf][adst[1]]);   \
    gl_lds(bsrc[0] + (k0), &Bs[buf][bdst[0]]);   \
    gl_lds(bsrc[1] + (k0), &Bs[buf][bdst[1]]);   \
    gl_lds(bsrc[2] + (k0), &Bs[buf][bdst[2]]);   \
    gl_lds(bsrc[3] + (k0), &Bs[buf][bdst[3]]);   \
  } while (0)

  K5_STAGE(0, 0);
  K5_STAGE(32, 1);

  const int NK = IDIM / 32;
  int c = 0, sb = 2;
  for (int kt = 0; kt < NK; ++kt) {
    if (kt + 2 < NK) {
      K5_STAGE((kt + 2) * 32, sb);
      asm volatile("s_waitcnt vmcnt(12)" ::: "memory");
    } else if (kt + 1 < NK) {
      asm volatile("s_waitcnt vmcnt(6)" ::: "memory");
    } else {
      asm volatile("s_waitcnt vmcnt(0)" ::: "memory");
    }
    __builtin_amdgcn_s_barrier();

    short8 af[4];
#pragma unroll
    for (int mf = 0; mf < 4; ++mf) af[mf] = *(const short8*)&As[c][afo[mf]];
#pragma unroll
    for (int nf = 0; nf < 8; ++nf) {
      short8 bd = *(const short8*)&Bs[c][bfo[nf]];
#pragma unroll
      for (int mf = 0; mf < 4; ++mf)
        acc[mf][nf] = __builtin_amdgcn_mfma_f32_16x16x32_bf16(af[mf], bd, acc[mf][nf], 0, 0, 0);
    }
    __builtin_amdgcn_s_barrier();
    c = (c == 2) ? 0 : c + 1;
    sb = (sb == 2) ? 0 : sb + 1;
  }
#undef K5_STAGE

  unsigned rows_left = n - row0;
#pragma unroll
  for (int mf = 0; mf < 4; ++mf)
#pragma unroll
    for (int j = 0; j < 4; ++j) {
      int rin = wr * 64 + mf * 16 + 4 * g + j;
      if ((unsigned)rin < rows_left) {
        size_t s = base + row0 + rin;
        u16* yrow = y + s * HDIM + col0 + wc * 128 + lr;
#pragma unroll
        for (int nf = 0; nf < 8; ++nf) yrow[nf * 16] = f2bf(acc[mf][nf][j]);
      }
    }
}

// ---------------- K6: combine out[t] = w0*y[s0] + w1*y[s1] ----------------
__global__ __launch_bounds__(512) void k6_combine(const u16* __restrict__ y,
                                                  const u16* __restrict__ tok2slot,
                                                  const float* __restrict__ slot_w,
                                                  float* __restrict__ out) {
  unsigned idx = blockIdx.x * 512 + threadIdx.x;  // one per 8 elems
  int t = idx >> 8;                               // HDIM/8 = 256 chunks per row
  int off = (idx & 255) * 8;
  int s0 = tok2slot[t * 2 + 0];
  int s1 = tok2slot[t * 2 + 1];
  float w0 = slot_w[s0];
  float w1 = slot_w[s1];
  short8 a = *(const short8*)(y + (size_t)s0 * HDIM + off);
  short8 b = *(const short8*)(y + (size_t)s1 * HDIM + off);
  float* o = out + (size_t)t * HDIM + off;
  float4 o0, o1;
  o0.x = w0 * bf2f((u16)a[0]) + w1 * bf2f((u16)b[0]);
  o0.y = w0 * bf2f((u16)a[1]) + w1 * bf2f((u16)b[1]);
  o0.z = w0 * bf2f((u16)a[2]) + w1 * bf2f((u16)b[2]);
  o0.w = w0 * bf2f((u16)a[3]) + w1 * bf2f((u16)b[3]);
  o1.x = w0 * bf2f((u16)a[4]) + w1 * bf2f((u16)b[4]);
  o1.y = w0 * bf2f((u16)a[5]) + w1 * bf2f((u16)b[5]);
  o1.z = w0 * bf2f((u16)a[6]) + w1 * bf2f((u16)b[6]);
  o1.w = w0 * bf2f((u16)a[7]) + w1 * bf2f((u16)b[7]);
  *(float4*)o = o0;
  *(float4*)(o + 4) = o1;
}

extern "C" void kernel_launch(void* const* d_in, const int* in_sizes, int n_in,
                              void* d_out, int out_size, void* d_ws, size_t ws_size,
                              hipStream_t stream) {
  const float* x = (const float*)d_in[0];
  const float* wgate = (const float*)d_in[1];
  const float* wg = (const float*)d_in[2];
  const float* wu = (const float*)d_in[3];
  const float* wd = (const float*)d_in[4];
  float* out = (float*)d_out;
  float* logits = out + (size_t)T_TOK * HDIM;

  const size_t XBF_OFF = 132096;
  const size_t ACT_OFF = XBF_OFF + (size_t)T_TOK * HDIM * 2;
  const size_t WGT_OFF = ACT_OFF + (size_t)2 * T_TOK * IDIM * 2;
  const size_t WUT_OFF = WGT_OFF + (size_t)NE * HDIM * IDIM * 2;
  const size_t WDT_OFF = WUT_OFF + (size_t)NE * HDIM * IDIM * 2;
  const size_t NEED_T3 = WDT_OFF + (size_t)NE * IDIM * HDIM * 2;  // 167,904,256 (proven R5)
  if (ws_size < NEED_T3) return;  // loud failure

  char* ws = (char*)d_ws;
  unsigned* meta = (unsigned*)ws;
  unsigned* cnt = meta + 0;
  unsigned* cursor = meta + 8;
  u16* slot_token = (u16*)(ws + 256);
  float* slot_w = (float*)(ws + 33024);
  u16* tok2slot = (u16*)(ws + 98560);
  u16* xbf = (u16*)(ws + XBF_OFF);
  u16* act = (u16*)(ws + ACT_OFF);
  u16* wgT = (u16*)(ws + WGT_OFF);
  u16* wuT = (u16*)(ws + WUT_OFF);
  u16* wdT = (u16*)(ws + WDT_OFF);
  u16* y = (u16*)(ws + WGT_OFF);  // reuses wgT+wuT (dead after k4)
  char* sel = (char*)act;         // dead before k4 writes act
  float* wt = (float*)((char*)act + 16384);

  hipMemsetAsync(cnt, 0, 32, stream);
  k0t_fused<<<T_TOK / 4 + 3 * 1024, 256, 0, stream>>>(
      x, wgate, xbf, logits, sel, wt, cnt, wg, wgT, wu, wuT, wd, wdT);
  k3_assign<<<T_TOK / 256, 256, 0, stream>>>(sel, wt, cnt, cursor, slot_token, slot_w, tok2slot);
  k4_gateup<<<dim3(T_TOK / 128, IDIM / 128, NE), 256, 0, stream>>>(xbf, wgT, wuT, slot_token,
                                                                   cnt, act);
  k5_down<<<dim3(T_TOK / 128, HDIM / 256, NE), 256, 0, stream>>>(act, wdT, cnt, y);
  k6_combine<<<T_TOK * HDIM / 8 / 512, 512, 0, stream>>>(y, tok2slot, slot_w, out);
}

// Round 20
// 411.653 us; speedup vs baseline: 1.5267x; 1.5267x over previous
//
#include <hip/hip_runtime.h>
#include <math.h>

#define T_TOK 8192
#define HDIM 2048
#define IDIM 1024
#define NE 8

typedef __attribute__((ext_vector_type(8))) short short8;
typedef __attribute__((ext_vector_type(4))) float f32x4;
typedef unsigned short u16;

__device__ inline u16 f2bf(float f) {
  unsigned u = __builtin_bit_cast(unsigned, f);
  u += 0x7fffu + ((u >> 16) & 1);  // RNE
  return (u16)(u >> 16);
}
__device__ inline float bf2f(u16 u) {
  unsigned v = (unsigned)u << 16;
  return __builtin_bit_cast(float, v);
}

// async global->LDS, 16B/lane. LDS dest = wave-uniform base + lane*16.
__device__ inline void gl_lds(const u16* g, u16* l) {
  __builtin_amdgcn_global_load_lds((const __attribute__((address_space(1))) unsigned int*)g,
                                   (__attribute__((address_space(3))) unsigned int*)l, 16, 0, 0);
}

// bf16 LDS tiles [row][32] (64B rows); chunk swizzle applied on the GLOBAL
// source address (m173): position p holds global chunk p ^ ((row>>1)&3).
// Frag read of granule g: row*32 + 8*(g ^ ((row>>1)&3)) -> measured 0 conflicts.
__device__ inline int rswz(int row, int g) { return row * 32 + 8 * (g ^ ((row >> 1) & 3)); }

// ---------- ws layout ----------
// 0       meta: cnt[8] cursor[8] (u32; memset'd)
// 256     slot_token u16[2T]  (32 KB)
// 33024   slot_w    f32[2T]   (64 KB)
// 98560   tok2slot  u16[2T]   (32 KB)   -> ends 131328
// 132096  xbf  bf16[T*H]      (33.5 MB)
// ACT     act  bf16[2T*I]     (33.5 MB)  (sel/wt stashed here pre-k4)
// WGT     wgT / wuT           (67 MB)    -> y bf16[2T*H] after k4 (exact fit)
// WDT     wdT                 (33.5 MB)  total 167,904,256 (proven R5)

// ---------------- K1: router + x->bf16 (NO atomics; wgate via LDS slab) ----------------
__global__ __launch_bounds__(256) void k1_router(const float* __restrict__ x,
                                                 const float* __restrict__ wgate,
                                                 u16* __restrict__ xb,
                                                 float* __restrict__ logits_out,
                                                 char* __restrict__ sel,
                                                 float* __restrict__ wt) {
  __shared__ float slab[256 * 9];  // 9216 B
  int tid = threadIdx.x;
  int wave = tid >> 6;
  int lane = tid & 63;
  int tok = blockIdx.x * 4 + wave;
  float acc[NE];
#pragma unroll
  for (int e = 0; e < NE; ++e) acc[e] = 0.f;
  const float4* xr = (const float4*)(x + (size_t)tok * HDIM);
  u16* xbrow = xb + (size_t)tok * HDIM;
  for (int c = 0; c < HDIM / 256; ++c) {
    if (c) __syncthreads();
    {
      const float4* wsrc = (const float4*)(wgate + (size_t)c * 2048 + tid * 8);
      float4 w0 = wsrc[0];
      float4 w1 = wsrc[1];
      float* sr = slab + tid * 9;
      sr[0] = w0.x; sr[1] = w0.y; sr[2] = w0.z; sr[3] = w0.w;
      sr[4] = w1.x; sr[5] = w1.y; sr[6] = w1.z; sr[7] = w1.w;
    }
    __syncthreads();
    float4 xv = xr[c * 64 + lane];
    int h = (c * 64 + lane) * 4;
    ushort4 o = make_ushort4(f2bf(xv.x), f2bf(xv.y), f2bf(xv.z), f2bf(xv.w));
    *(ushort4*)(xbrow + h) = o;
    const float xs[4] = {xv.x, xv.y, xv.z, xv.w};
#pragma unroll
    for (int j = 0; j < 4; ++j) {
      const float* wrow = slab + (size_t)(4 * lane + j) * 9;
#pragma unroll
      for (int e = 0; e < NE; ++e) acc[e] += xs[j] * wrow[e];
    }
  }
#pragma unroll
  for (int e = 0; e < NE; ++e) {
    float v = acc[e];
#pragma unroll
    for (int off = 32; off; off >>= 1) v += __shfl_xor(v, off, 64);
    acc[e] = v;
  }
  if (lane == 0) {
    float m = acc[0];
#pragma unroll
    for (int e = 0; e < NE; ++e) {
      logits_out[(size_t)tok * NE + e] = acc[e];
      m = fmaxf(m, acc[e]);
    }
    float p[NE];
#pragma unroll
    for (int e = 0; e < NE; ++e) p[e] = expf(acc[e] - m);
    int b0 = 0;
    float v0 = p[0];
#pragma unroll
    for (int e = 1; e < NE; ++e)
      if (p[e] > v0) { v0 = p[e]; b0 = e; }
    int b1 = -1;
    float v1 = -1.f;
#pragma unroll
    for (int e = 0; e < NE; ++e)
      if (e != b0 && p[e] > v1) { v1 = p[e]; b1 = e; }
    float denom = v0 + v1;
    sel[tok * 2 + 0] = (char)b0;
    sel[tok * 2 + 1] = (char)b1;
    wt[tok * 2 + 0] = v0 / denom;
    wt[tok * 2 + 1] = v1 / denom;
  }
}

// ---------------- KT: weight transpose+cvt, 3 tiles/block, reg-pipelined ----------------
__global__ __launch_bounds__(256) void kt_all(const float* __restrict__ wg, u16* __restrict__ wgT,
                                              const float* __restrict__ wu, u16* __restrict__ wuT,
                                              const float* __restrict__ wd, u16* __restrict__ wdT) {
  __shared__ __align__(16) u16 t[2][64][72];  // 18,432 B
  int tid = threadIdx.x;
  unsigned tb = blockIdx.x;  // 0..2047
  const float* srcp[3];
  u16* dstp[3];
  int kb[3], nb[3], KK[3], NN[3];
#pragma unroll
  for (int i = 0; i < 3; ++i) {
    unsigned ti = 3 * tb + i;
    unsigned mat = ti / 2048u;  // 0=wg 1=wu 2=wd
    unsigned rem = ti % 2048u;
    unsigned e = rem >> 8;
    unsigned tile = rem & 255u;
    KK[i] = (mat == 2) ? IDIM : HDIM;
    NN[i] = (mat == 2) ? HDIM : IDIM;
    srcp[i] = (mat == 0 ? wg : mat == 1 ? wu : wd) + (size_t)e * KK[i] * NN[i];
    dstp[i] = (mat == 0 ? wgT : mat == 1 ? wuT : wdT) + (size_t)e * KK[i] * NN[i];
    int ntn = NN[i] >> 6;
    kb[i] = (int)(tile / ntn) * 128;
    nb[i] = (int)(tile % ntn) * 64;
  }
  int lk = tid >> 4, ln = (tid & 15) * 4;
  int nrow = tid >> 2, c16 = (tid & 3) * 16;

#define LOADT(vv, i)                                                                        \
  {                                                                                         \
    _Pragma("unroll") for (int st = 0; st < 2; ++st) _Pragma("unroll") for (int p = 0;      \
                                                                            p < 4; ++p)     \
        vv[st * 4 + p] = *(const float4*)(srcp[i] +                                         \
                                          (size_t)(kb[i] + st * 64 + lk + 16 * p) * NN[i] + \
                                          nb[i] + ln);                                      \
  }
#define LDSW(vv)                                          \
  {                                                       \
    _Pragma("unroll") for (int st = 0; st < 2; ++st)      \
        _Pragma("unroll") for (int p = 0; p < 4; ++p) {   \
      int k = lk + 16 * p;                                \
      t[st][ln + 0][k] = f2bf(vv[st * 4 + p].x);          \
      t[st][ln + 1][k] = f2bf(vv[st * 4 + p].y);          \
      t[st][ln + 2][k] = f2bf(vv[st * 4 + p].z);          \
      t[st][ln + 3][k] = f2bf(vv[st * 4 + p].w);          \
    }                                                     \
  }
#define WOUT(i)                                                          \
  {                                                                      \
    u16* drow = dstp[i] + (size_t)(nb[i] + nrow) * KK[i] + kb[i];        \
    _Pragma("unroll") for (int st = 0; st < 2; ++st) {                   \
      short8 o0 = *(const short8*)&t[st][nrow][c16];                     \
      short8 o1 = *(const short8*)&t[st][nrow][c16 + 8];                 \
      *(short8*)(drow + st * 64 + c16) = o0;                             \
      *(short8*)(drow + st * 64 + c16 + 8) = o1;                         \
    }                                                                    \
  }

  float4 va[8], vb[8];
  LOADT(va, 0);
  LOADT(vb, 1);
  LDSW(va);
  LOADT(va, 2);
  __syncthreads();
  WOUT(0);
  __syncthreads();
  LDSW(vb);
  __syncthreads();
  WOUT(1);
  __syncthreads();
  LDSW(va);
  __syncthreads();
  WOUT(2);
#undef LOADT
#undef LDSW
#undef WOUT
}

// ---------------- K2: count experts (LDS histogram -> 64 global atomics) ----------------
__global__ __launch_bounds__(256) void k2_count(const char* __restrict__ sel,
                                                unsigned* __restrict__ cnt) {
  __shared__ unsigned h[NE];
  if (threadIdx.x < NE) h[threadIdx.x] = 0;
  __syncthreads();
  int base = (blockIdx.x * 256 + threadIdx.x) * 8;
#pragma unroll
  for (int i = 0; i < 8; ++i) atomicAdd(&h[(int)sel[base + i]], 1u);
  __syncthreads();
  if (threadIdx.x < NE) atomicAdd(&cnt[threadIdx.x], h[threadIdx.x]);
}

// ---------------- K3: hierarchical slot assignment (8 global atomics/block) ----------------
__global__ __launch_bounds__(256) void k3_assign(const char* __restrict__ sel,
                                                 const float* __restrict__ wt,
                                                 const unsigned* __restrict__ cnt,
                                                 unsigned* __restrict__ cursor,
                                                 u16* __restrict__ slot_token,
                                                 float* __restrict__ slot_w,
                                                 u16* __restrict__ tok2slot) {
  __shared__ unsigned lh[NE], bb[NE];
  int tid = threadIdx.x;
  if (tid < NE) lh[tid] = 0;
  __syncthreads();
  int t = blockIdx.x * 256 + tid;
  int e0 = sel[t * 2 + 0];
  int e1 = sel[t * 2 + 1];
  unsigned r0 = atomicAdd(&lh[e0], 1u);  // LDS atomic: block-local rank
  unsigned r1 = atomicAdd(&lh[e1], 1u);
  __syncthreads();
  if (tid < NE) bb[tid] = atomicAdd(&cursor[tid], lh[tid]);  // block range reservation
  __syncthreads();
  unsigned offv[NE];
  unsigned s = 0;
#pragma unroll
  for (int e = 0; e < NE; ++e) {
    offv[e] = s;
    s += cnt[e];
  }
  unsigned s0 = offv[e0] + bb[e0] + r0;
  unsigned s1 = offv[e1] + bb[e1] + r1;
  slot_token[s0] = (u16)t;
  slot_w[s0] = wt[t * 2 + 0];
  tok2slot[t * 2 + 0] = (u16)s0;
  slot_token[s1] = (u16)t;
  slot_w[s1] = wt[t * 2 + 1];
  tok2slot[t * 2 + 1] = (u16)s1;
}

// Bijective XCD swizzle for 64x8x8 = 4096-block grids (8 XCDs, 512/XCD).
__device__ inline void xcd_decomp(int& bx, int& by, int& be) {
  unsigned bid = blockIdx.x + 64u * (blockIdx.y + 8u * blockIdx.z);
  unsigned swz = (bid & 7u) * 512u + (bid >> 3);
  bx = swz & 63u;
  unsigned rem = swz >> 6;
  by = rem & 7u;
  be = rem >> 3;
}

// local exclusive-prefix over cnt (8 uniform L2-hot loads)
__device__ inline unsigned prefix_base(const unsigned* cnt, int e) {
  unsigned b = 0;
#pragma unroll
  for (int i = 0; i < NE; ++i) b += (i < e) ? cnt[i] : 0u;
  return b;
}

// ---------------- K4: MFMA gate+up + silu -> bf16 act (R9/R13 structure) ----------------
__global__ __launch_bounds__(256, 2) void k4_gateup(
    const u16* __restrict__ xb, const u16* __restrict__ wgT, const u16* __restrict__ wuT,
    const u16* __restrict__ slot_token, const unsigned* __restrict__ cnt,
    u16* __restrict__ act) {
  int bx, by, e;
  xcd_decomp(bx, by, e);
  unsigned n = cnt[e];
  unsigned row0 = (unsigned)bx * 128;
  if (row0 >= n) return;
  unsigned base = prefix_base(cnt, e);
  int col0 = by * 128;

  __shared__ __align__(16) u16 As[3][128 * 32];  // 24 KB
  __shared__ __align__(16) u16 Bg[3][128 * 32];  // 24 KB
  __shared__ __align__(16) u16 Bu[3][128 * 32];  // 24 KB

  int tid = threadIdx.x;
  int w = tid >> 6, l = tid & 63;
  int wr = w >> 1, wc = w & 1;
  int lr = l & 15, g = l >> 4;

  const u16* asrc[2];
  int adst[2];
#pragma unroll
  for (int i = 0; i < 2; ++i) {
    int r = 32 * w + 16 * i + (l >> 2);
    unsigned grow = row0 + (unsigned)r;
    unsigned slot = base + (grow < n ? grow : 0);
    int chunk = (l & 3) ^ ((r >> 1) & 3);
    asrc[i] = xb + (size_t)slot_token[slot] * HDIM + 8 * chunk;
    adst[i] = (32 * w + 16 * i) * 32;
  }
  const u16* bgsrc[2];
  const u16* busrc[2];
  int bdst[2];
#pragma unroll
  for (int i = 0; i < 2; ++i) {
    int nn = 32 * w + 16 * i + (l >> 2);
    int chunk = (l & 3) ^ ((nn >> 1) & 3);
    size_t o = (size_t)e * HDIM * IDIM + (size_t)(col0 + nn) * HDIM + 8 * chunk;
    bgsrc[i] = wgT + o;
    busrc[i] = wuT + o;
    bdst[i] = (32 * w + 16 * i) * 32;
  }

  int afo[4], bfo[4];
#pragma unroll
  for (int mf = 0; mf < 4; ++mf) afo[mf] = rswz(wr * 64 + mf * 16 + lr, g);
#pragma unroll
  for (int nf = 0; nf < 4; ++nf) bfo[nf] = rswz(wc * 64 + nf * 16 + lr, g);

  f32x4 accg[4][4] = {};
  f32x4 accu[4][4] = {};

#define K4_STAGE(k0, buf)                           \
  do {                                              \
    gl_lds(asrc[0] + (k0), &As[buf][adst[0]]);      \
    gl_lds(asrc[1] + (k0), &As[buf][adst[1]]);      \
    gl_lds(bgsrc[0] + (k0), &Bg[buf][bdst[0]]);     \
    gl_lds(bgsrc[1] + (k0), &Bg[buf][bdst[1]]);     \
    gl_lds(busrc[0] + (k0), &Bu[buf][bdst[0]]);     \
    gl_lds(busrc[1] + (k0), &Bu[buf][bdst[1]]);     \
  } while (0)

  K4_STAGE(0, 0);
  K4_STAGE(32, 1);  // 12 loads in flight

  const int NK = HDIM / 32;
  int c = 0, sb = 2;
  for (int kt = 0; kt < NK; ++kt) {
    if (kt + 2 < NK) {
      K4_STAGE((kt + 2) * 32, sb);                       // 18 in flight
      asm volatile("s_waitcnt vmcnt(12)" ::: "memory");  // tile kt landed
    } else if (kt + 1 < NK) {
      asm volatile("s_waitcnt vmcnt(6)" ::: "memory");
    } else {
      asm volatile("s_waitcnt vmcnt(0)" ::: "memory");
    }
    __builtin_amdgcn_s_barrier();

    short8 af[4];
#pragma unroll
    for (int mf = 0; mf < 4; ++mf) af[mf] = *(const short8*)&As[c][afo[mf]];
#pragma unroll
    for (int nf = 0; nf < 4; ++nf) {
      short8 bgf = *(const short8*)&Bg[c][bfo[nf]];
      short8 buf = *(const short8*)&Bu[c][bfo[nf]];
#pragma unroll
      for (int mf = 0; mf < 4; ++mf) {
        accg[mf][nf] = __builtin_amdgcn_mfma_f32_16x16x32_bf16(af[mf], bgf, accg[mf][nf], 0, 0, 0);
        accu[mf][nf] = __builtin_amdgcn_mfma_f32_16x16x32_bf16(af[mf], buf, accu[mf][nf], 0, 0, 0);
      }
    }
    __builtin_amdgcn_s_barrier();
    c = (c == 2) ? 0 : c + 1;
    sb = (sb == 2) ? 0 : sb + 1;
  }
#undef K4_STAGE

  unsigned rows_left = n - row0;
#pragma unroll
  for (int mf = 0; mf < 4; ++mf)
#pragma unroll
    for (int nf = 0; nf < 4; ++nf)
#pragma unroll
      for (int j = 0; j < 4; ++j) {
        int rin = wr * 64 + mf * 16 + 4 * g + j;
        if ((unsigned)rin < rows_left) {
          size_t s = base + row0 + rin;
          int col = col0 + wc * 64 + nf * 16 + lr;
          float gg = accg[mf][nf][j];
          float uu = accu[mf][nf][j];
          float v = (gg / (1.f + expf(-gg))) * uu;
          act[s * IDIM + col] = f2bf(v);
        }
      }
}

// ---------------- K5: MFMA down -> bf16 y (R9/R13 structure) ----------------
__global__ __launch_bounds__(256, 2) void k5_down(
    const u16* __restrict__ act, const u16* __restrict__ wdT,
    const unsigned* __restrict__ cnt, u16* __restrict__ y) {
  int bx, by, e;
  xcd_decomp(bx, by, e);
  unsigned n = cnt[e];
  unsigned row0 = (unsigned)bx * 128;
  if (row0 >= n) return;
  unsigned base = prefix_base(cnt, e);
  int col0 = by * 256;

  __shared__ __align__(16) u16 As[3][128 * 32];  // 24 KB
  __shared__ __align__(16) u16 Bs[3][256 * 32];  // 48 KB

  int tid = threadIdx.x;
  int w = tid >> 6, l = tid & 63;
  int wr = w >> 1, wc = w & 1;
  int lr = l & 15, g = l >> 4;

  const u16* asrc[2];
  int adst[2];
#pragma unroll
  for (int i = 0; i < 2; ++i) {
    int r = 32 * w + 16 * i + (l >> 2);
    unsigned grow = row0 + (unsigned)r;
    unsigned slot = base + (grow < n ? grow : 0);
    int chunk = (l & 3) ^ ((r >> 1) & 3);
    asrc[i] = act + (size_t)slot * IDIM + 8 * chunk;
    adst[i] = (32 * w + 16 * i) * 32;
  }
  const u16* bsrc[4];
  int bdst[4];
#pragma unroll
  for (int i = 0; i < 4; ++i) {
    int nn = 64 * w + 16 * i + (l >> 2);
    int chunk = (l & 3) ^ ((nn >> 1) & 3);
    bsrc[i] = wdT + (size_t)e * IDIM * HDIM + (size_t)(col0 + nn) * IDIM + 8 * chunk;
    bdst[i] = (64 * w + 16 * i) * 32;
  }

  int afo[4], bfo[8];
#pragma unroll
  for (int mf = 0; mf < 4; ++mf) afo[mf] = rswz(wr * 64 + mf * 16 + lr, g);
#pragma unroll
  for (int nf = 0; nf < 8; ++nf) bfo[nf] = rswz(wc * 128 + nf * 16 + lr, g);

  f32x4 acc[4][8] = {};

#define K5_STAGE(k0, buf)                        \
  do {                                           \
    gl_lds(asrc[0] + (k0), &As[buf][adst[0]]);   \
    gl_lds(asrc[1] + (k0), &As[buf][adst[1]]);   \
    gl_lds(bsrc[0] + (k0), &Bs[buf][bdst[0]]);   \
    gl_lds(bsrc[1] + (k0), &Bs[buf][bdst[1]]);   \
    gl_lds(bsrc[2] + (k0), &Bs[buf][bdst[2]]);   \
    gl_lds(bsrc[3] + (k0), &Bs[buf][bdst[3]]);   \
  } while (0)

  K5_STAGE(0, 0);
  K5_STAGE(32, 1);

  const int NK = IDIM / 32;
  int c = 0, sb = 2;
  for (int kt = 0; kt < NK; ++kt) {
    if (kt + 2 < NK) {
      K5_STAGE((kt + 2) * 32, sb);
      asm volatile("s_waitcnt vmcnt(12)" ::: "memory");
    } else if (kt + 1 < NK) {
      asm volatile("s_waitcnt vmcnt(6)" ::: "memory");
    } else {
      asm volatile("s_waitcnt vmcnt(0)" ::: "memory");
    }
    __builtin_amdgcn_s_barrier();

    short8 af[4];
#pragma unroll
    for (int mf = 0; mf < 4; ++mf) af[mf] = *(const short8*)&As[c][afo[mf]];
#pragma unroll
    for (int nf = 0; nf < 8; ++nf) {
      short8 bd = *(const short8*)&Bs[c][bfo[nf]];
#pragma unroll
      for (int mf = 0; mf < 4; ++mf)
        acc[mf][nf] = __builtin_amdgcn_mfma_f32_16x16x32_bf16(af[mf], bd, acc[mf][nf], 0, 0, 0);
    }
    __builtin_amdgcn_s_barrier();
    c = (c == 2) ? 0 : c + 1;
    sb = (sb == 2) ? 0 : sb + 1;
  }
#undef K5_STAGE

  unsigned rows_left = n - row0;
#pragma unroll
  for (int mf = 0; mf < 4; ++mf)
#pragma unroll
    for (int j = 0; j < 4; ++j) {
      int rin = wr * 64 + mf * 16 + 4 * g + j;
      if ((unsigned)rin < rows_left) {
        size_t s = base + row0 + rin;
        u16* yrow = y + s * HDIM + col0 + wc * 128 + lr;
#pragma unroll
        for (int nf = 0; nf < 8; ++nf) yrow[nf * 16] = f2bf(acc[mf][nf][j]);
      }
    }
}

// ---------------- K6: combine out[t] = w0*y[s0] + w1*y[s1] ----------------
__global__ __launch_bounds__(512) void k6_combine(const u16* __restrict__ y,
                                                  const u16* __restrict__ tok2slot,
                                                  const float* __restrict__ slot_w,
                                                  float* __restrict__ out) {
  unsigned idx = blockIdx.x * 512 + threadIdx.x;  // one per 8 elems
  int t = idx >> 8;                               // HDIM/8 = 256 chunks per row
  int off = (idx & 255) * 8;
  int s0 = tok2slot[t * 2 + 0];
  int s1 = tok2slot[t * 2 + 1];
  float w0 = slot_w[s0];
  float w1 = slot_w[s1];
  short8 a = *(const short8*)(y + (size_t)s0 * HDIM + off);
  short8 b = *(const short8*)(y + (size_t)s1 * HDIM + off);
  float* o = out + (size_t)t * HDIM + off;
  float4 o0, o1;
  o0.x = w0 * bf2f((u16)a[0]) + w1 * bf2f((u16)b[0]);
  o0.y = w0 * bf2f((u16)a[1]) + w1 * bf2f((u16)b[1]);
  o0.z = w0 * bf2f((u16)a[2]) + w1 * bf2f((u16)b[2]);
  o0.w = w0 * bf2f((u16)a[3]) + w1 * bf2f((u16)b[3]);
  o1.x = w0 * bf2f((u16)a[4]) + w1 * bf2f((u16)b[4]);
  o1.y = w0 * bf2f((u16)a[5]) + w1 * bf2f((u16)b[5]);
  o1.z = w0 * bf2f((u16)a[6]) + w1 * bf2f((u16)b[6]);
  o1.w = w0 * bf2f((u16)a[7]) + w1 * bf2f((u16)b[7]);
  *(float4*)o = o0;
  *(float4*)(o + 4) = o1;
}

extern "C" void kernel_launch(void* const* d_in, const int* in_sizes, int n_in,
                              void* d_out, int out_size, void* d_ws, size_t ws_size,
                              hipStream_t stream) {
  const float* x = (const float*)d_in[0];
  const float* wgate = (const float*)d_in[1];
  const float* wg = (const float*)d_in[2];
  const float* wu = (const float*)d_in[3];
  const float* wd = (const float*)d_in[4];
  float* out = (float*)d_out;
  float* logits = out + (size_t)T_TOK * HDIM;

  const size_t XBF_OFF = 132096;
  const size_t ACT_OFF = XBF_OFF + (size_t)T_TOK * HDIM * 2;
  const size_t WGT_OFF = ACT_OFF + (size_t)2 * T_TOK * IDIM * 2;
  const size_t WUT_OFF = WGT_OFF + (size_t)NE * HDIM * IDIM * 2;
  const size_t WDT_OFF = WUT_OFF + (size_t)NE * HDIM * IDIM * 2;
  const size_t NEED_T3 = WDT_OFF + (size_t)NE * IDIM * HDIM * 2;  // 167,904,256 (proven R5)
  if (ws_size < NEED_T3) return;  // loud failure

  char* ws = (char*)d_ws;
  unsigned* meta = (unsigned*)ws;
  unsigned* cnt = meta + 0;
  unsigned* cursor = meta + 8;
  u16* slot_token = (u16*)(ws + 256);
  float* slot_w = (float*)(ws + 33024);
  u16* tok2slot = (u16*)(ws + 98560);
  u16* xbf = (u16*)(ws + XBF_OFF);
  u16* act = (u16*)(ws + ACT_OFF);
  u16* wgT = (u16*)(ws + WGT_OFF);
  u16* wuT = (u16*)(ws + WUT_OFF);
  u16* wdT = (u16*)(ws + WDT_OFF);
  u16* y = (u16*)(ws + WGT_OFF);  // reuses wgT+wuT (dead after k4)
  char* sel = (char*)act;         // dead before k4 writes act
  float* wt = (float*)((char*)act + 16384);

  hipMemsetAsync(meta, 0, 64, stream);  // cnt[8] + cursor[8]
  k1_router<<<T_TOK / 4, 256, 0, stream>>>(x, wgate, xbf, logits, sel, wt);
  kt_all<<<2048, 256, 0, stream>>>(wg, wgT, wu, wuT, wd, wdT);
  k2_count<<<T_TOK * 2 / (256 * 8), 256, 0, stream>>>(sel, cnt);
  k3_assign<<<T_TOK / 256, 256, 0, stream>>>(sel, wt, cnt, cursor, slot_token, slot_w, tok2slot);
  k4_gateup<<<dim3(T_TOK / 128, IDIM / 128, NE), 256, 0, stream>>>(xbf, wgT, wuT, slot_token,
                                                                   cnt, act);
  k5_down<<<dim3(T_TOK / 128, HDIM / 256, NE), 256, 0, stream>>>(act, wdT, cnt, y);
  k6_combine<<<T_TOK * HDIM / 8 / 512, 512, 0, stream>>>(y, tok2slot, slot_w, out);
}

// Round 21
// 403.738 us; speedup vs baseline: 1.5566x; 1.0196x over previous
//
#include <hip/hip_runtime.h>
#include <math.h>

#define T_TOK 8192
#define HDIM 2048
#define IDIM 1024
#define NE 8

typedef __attribute__((ext_vector_type(8))) short short8;
typedef __attribute__((ext_vector_type(4))) float f32x4;
typedef unsigned short u16;

__device__ inline u16 f2bf(float f) {
  unsigned u = __builtin_bit_cast(unsigned, f);
  u += 0x7fffu + ((u >> 16) & 1);  // RNE
  return (u16)(u >> 16);
}
__device__ inline float bf2f(u16 u) {
  unsigned v = (unsigned)u << 16;
  return __builtin_bit_cast(float, v);
}

// async global->LDS, 16B/lane. LDS dest = wave-uniform base + lane*16.
__device__ inline void gl_lds(const u16* g, u16* l) {
  __builtin_amdgcn_global_load_lds((const __attribute__((address_space(1))) unsigned int*)g,
                                   (__attribute__((address_space(3))) unsigned int*)l, 16, 0, 0);
}

// bf16 LDS tiles [row][32] (64B rows); chunk swizzle applied on the GLOBAL
// source address (m173): position p holds global chunk p ^ ((row>>1)&3).
// Frag read of granule g: row*32 + 8*(g ^ ((row>>1)&3)) -> measured 0 conflicts.
__device__ inline int rswz(int row, int g) { return row * 32 + 8 * (g ^ ((row >> 1) & 3)); }

// ---------- ws layout ----------
// 0       meta: cnt[8] cursor[8] (u32; memset'd)
// 256     slot_token u16[2T]  (32 KB)
// 33024   slot_w    f32[2T]   (64 KB)
// 98560   tok2slot  u16[2T]   (32 KB)   -> ends 131328
// 132096  xbf  bf16[T*H]      (33.5 MB)
// ACT     act  bf16[2T*I]     (33.5 MB)  (sel/wt stashed here pre-k4)
// WGT     wgT / wuT           (67 MB)    -> y bf16[2T*H] after k4 (exact fit)
// WDT     wdT                 (33.5 MB)  total 167,904,256 (proven R5)

// ---------------- K01T: FUSED router (blocks 0..2047, NO atomics) &
// transpose (blocks 2048..4095, 3 tiles/block, reg-pipelined).
// Both arms atomic-free & independent -> dispatch ~= max(router, transpose).
__global__ __launch_bounds__(256) void k01t_fused(
    const float* __restrict__ x, const float* __restrict__ wgate, u16* __restrict__ xb,
    float* __restrict__ logits_out, char* __restrict__ sel, float* __restrict__ wt,
    const float* __restrict__ wg, u16* __restrict__ wgT, const float* __restrict__ wu,
    u16* __restrict__ wuT, const float* __restrict__ wd, u16* __restrict__ wdT) {
  __shared__ __align__(16) unsigned char smem[18432];
  unsigned bid = blockIdx.x;
  int tid = threadIdx.x;
  if (bid < T_TOK / 4) {
    // ---- router + x->bf16 (wgate via LDS slab; NO atomics) ----
    float* slab = (float*)smem;  // [256][9] f32, 9216 B
    int wave = tid >> 6;
    int lane = tid & 63;
    int tok = bid * 4 + wave;
    float acc[NE];
#pragma unroll
    for (int e = 0; e < NE; ++e) acc[e] = 0.f;
    const float4* xr = (const float4*)(x + (size_t)tok * HDIM);
    u16* xbrow = xb + (size_t)tok * HDIM;
    for (int c = 0; c < HDIM / 256; ++c) {
      if (c) __syncthreads();
      {
        const float4* wsrc = (const float4*)(wgate + (size_t)c * 2048 + tid * 8);
        float4 w0 = wsrc[0];
        float4 w1 = wsrc[1];
        float* sr = slab + tid * 9;
        sr[0] = w0.x; sr[1] = w0.y; sr[2] = w0.z; sr[3] = w0.w;
        sr[4] = w1.x; sr[5] = w1.y; sr[6] = w1.z; sr[7] = w1.w;
      }
      __syncthreads();
      float4 xv = xr[c * 64 + lane];
      int h = (c * 64 + lane) * 4;
      ushort4 o = make_ushort4(f2bf(xv.x), f2bf(xv.y), f2bf(xv.z), f2bf(xv.w));
      *(ushort4*)(xbrow + h) = o;
      const float xs[4] = {xv.x, xv.y, xv.z, xv.w};
#pragma unroll
      for (int j = 0; j < 4; ++j) {
        const float* wrow = slab + (size_t)(4 * lane + j) * 9;
#pragma unroll
        for (int e = 0; e < NE; ++e) acc[e] += xs[j] * wrow[e];
      }
    }
#pragma unroll
    for (int e = 0; e < NE; ++e) {
      float v = acc[e];
#pragma unroll
      for (int off = 32; off; off >>= 1) v += __shfl_xor(v, off, 64);
      acc[e] = v;
    }
    if (lane == 0) {
      float m = acc[0];
#pragma unroll
      for (int e = 0; e < NE; ++e) {
        logits_out[(size_t)tok * NE + e] = acc[e];
        m = fmaxf(m, acc[e]);
      }
      float p[NE];
#pragma unroll
      for (int e = 0; e < NE; ++e) p[e] = expf(acc[e] - m);
      int b0 = 0;
      float v0 = p[0];
#pragma unroll
      for (int e = 1; e < NE; ++e)
        if (p[e] > v0) { v0 = p[e]; b0 = e; }
      int b1 = -1;
      float v1 = -1.f;
#pragma unroll
      for (int e = 0; e < NE; ++e)
        if (e != b0 && p[e] > v1) { v1 = p[e]; b1 = e; }
      float denom = v0 + v1;
      sel[tok * 2 + 0] = (char)b0;
      sel[tok * 2 + 1] = (char)b1;
      wt[tok * 2 + 0] = v0 / denom;
      wt[tok * 2 + 1] = v1 / denom;
    }
  } else {
    // ---- transpose+cvt: dst[n][k] = bf16(src[k][n]); 3 tiles, reg-pipelined ----
    typedef u16 (*tile_t)[64][72];
    tile_t t = (tile_t)smem;  // [2][64][72] u16 = 18,432 B
    unsigned tb = bid - T_TOK / 4;  // 0..2047
    const float* srcp[3];
    u16* dstp[3];
    int kb[3], nb[3], KK[3], NN[3];
#pragma unroll
    for (int i = 0; i < 3; ++i) {
      unsigned ti = 3 * tb + i;
      unsigned mat = ti / 2048u;  // 0=wg 1=wu 2=wd
      unsigned rem = ti % 2048u;
      unsigned e = rem >> 8;
      unsigned tile = rem & 255u;
      KK[i] = (mat == 2) ? IDIM : HDIM;
      NN[i] = (mat == 2) ? HDIM : IDIM;
      srcp[i] = (mat == 0 ? wg : mat == 1 ? wu : wd) + (size_t)e * KK[i] * NN[i];
      dstp[i] = (mat == 0 ? wgT : mat == 1 ? wuT : wdT) + (size_t)e * KK[i] * NN[i];
      int ntn = NN[i] >> 6;
      kb[i] = (int)(tile / ntn) * 128;
      nb[i] = (int)(tile % ntn) * 64;
    }
    int lk = tid >> 4, ln = (tid & 15) * 4;
    int nrow = tid >> 2, c16 = (tid & 3) * 16;

#define LOADT(vv, i)                                                                        \
  {                                                                                         \
    _Pragma("unroll") for (int st = 0; st < 2; ++st) _Pragma("unroll") for (int p = 0;      \
                                                                            p < 4; ++p)     \
        vv[st * 4 + p] = *(const float4*)(srcp[i] +                                         \
                                          (size_t)(kb[i] + st * 64 + lk + 16 * p) * NN[i] + \
                                          nb[i] + ln);                                      \
  }
#define LDSW(vv)                                          \
  {                                                       \
    _Pragma("unroll") for (int st = 0; st < 2; ++st)      \
        _Pragma("unroll") for (int p = 0; p < 4; ++p) {   \
      int k = lk + 16 * p;                                \
      t[st][ln + 0][k] = f2bf(vv[st * 4 + p].x);          \
      t[st][ln + 1][k] = f2bf(vv[st * 4 + p].y);          \
      t[st][ln + 2][k] = f2bf(vv[st * 4 + p].z);          \
      t[st][ln + 3][k] = f2bf(vv[st * 4 + p].w);          \
    }                                                     \
  }
#define WOUT(i)                                                          \
  {                                                                      \
    u16* drow = dstp[i] + (size_t)(nb[i] + nrow) * KK[i] + kb[i];        \
    _Pragma("unroll") for (int st = 0; st < 2; ++st) {                   \
      short8 o0 = *(const short8*)&t[st][nrow][c16];                     \
      short8 o1 = *(const short8*)&t[st][nrow][c16 + 8];                 \
      *(short8*)(drow + st * 64 + c16) = o0;                             \
      *(short8*)(drow + st * 64 + c16 + 8) = o1;                         \
    }                                                                    \
  }

    float4 va[8], vb[8];
    LOADT(va, 0);
    LOADT(vb, 1);
    LDSW(va);
    LOADT(va, 2);
    __syncthreads();
    WOUT(0);
    __syncthreads();
    LDSW(vb);
    __syncthreads();
    WOUT(1);
    __syncthreads();
    LDSW(va);
    __syncthreads();
    WOUT(2);
#undef LOADT
#undef LDSW
#undef WOUT
  }
}

// ---------------- K2: count experts (LDS histogram -> 64 global atomics) ----------------
__global__ __launch_bounds__(256) void k2_count(const char* __restrict__ sel,
                                                unsigned* __restrict__ cnt) {
  __shared__ unsigned h[NE];
  if (threadIdx.x < NE) h[threadIdx.x] = 0;
  __syncthreads();
  int base = (blockIdx.x * 256 + threadIdx.x) * 8;
#pragma unroll
  for (int i = 0; i < 8; ++i) atomicAdd(&h[(int)sel[base + i]], 1u);
  __syncthreads();
  if (threadIdx.x < NE) atomicAdd(&cnt[threadIdx.x], h[threadIdx.x]);
}

// ---------------- K3: hierarchical slot assignment (8 global atomics/block) ----------------
__global__ __launch_bounds__(256) void k3_assign(const char* __restrict__ sel,
                                                 const float* __restrict__ wt,
                                                 const unsigned* __restrict__ cnt,
                                                 unsigned* __restrict__ cursor,
                                                 u16* __restrict__ slot_token,
                                                 float* __restrict__ slot_w,
                                                 u16* __restrict__ tok2slot) {
  __shared__ unsigned lh[NE], bb[NE];
  int tid = threadIdx.x;
  if (tid < NE) lh[tid] = 0;
  __syncthreads();
  int t = blockIdx.x * 256 + tid;
  int e0 = sel[t * 2 + 0];
  int e1 = sel[t * 2 + 1];
  unsigned r0 = atomicAdd(&lh[e0], 1u);  // LDS atomic: block-local rank
  unsigned r1 = atomicAdd(&lh[e1], 1u);
  __syncthreads();
  if (tid < NE) bb[tid] = atomicAdd(&cursor[tid], lh[tid]);  // block range reservation
  __syncthreads();
  unsigned offv[NE];
  unsigned s = 0;
#pragma unroll
  for (int e = 0; e < NE; ++e) {
    offv[e] = s;
    s += cnt[e];
  }
  unsigned s0 = offv[e0] + bb[e0] + r0;
  unsigned s1 = offv[e1] + bb[e1] + r1;
  slot_token[s0] = (u16)t;
  slot_w[s0] = wt[t * 2 + 0];
  tok2slot[t * 2 + 0] = (u16)s0;
  slot_token[s1] = (u16)t;
  slot_w[s1] = wt[t * 2 + 1];
  tok2slot[t * 2 + 1] = (u16)s1;
}

// Bijective XCD swizzle for 64x8x8 = 4096-block grids (8 XCDs, 512/XCD).
__device__ inline void xcd_decomp(int& bx, int& by, int& be) {
  unsigned bid = blockIdx.x + 64u * (blockIdx.y + 8u * blockIdx.z);
  unsigned swz = (bid & 7u) * 512u + (bid >> 3);
  bx = swz & 63u;
  unsigned rem = swz >> 6;
  by = rem & 7u;
  be = rem >> 3;
}

// local exclusive-prefix over cnt (8 uniform L2-hot loads)
__device__ inline unsigned prefix_base(const unsigned* cnt, int e) {
  unsigned b = 0;
#pragma unroll
  for (int i = 0; i < NE; ++i) b += (i < e) ? cnt[i] : 0u;
  return b;
}

// ---------------- K4: MFMA gate+up + silu -> bf16 act (R9/R13 structure) ----------------
__global__ __launch_bounds__(256, 2) void k4_gateup(
    const u16* __restrict__ xb, const u16* __restrict__ wgT, const u16* __restrict__ wuT,
    const u16* __restrict__ slot_token, const unsigned* __restrict__ cnt,
    u16* __restrict__ act) {
  int bx, by, e;
  xcd_decomp(bx, by, e);
  unsigned n = cnt[e];
  unsigned row0 = (unsigned)bx * 128;
  if (row0 >= n) return;
  unsigned base = prefix_base(cnt, e);
  int col0 = by * 128;

  __shared__ __align__(16) u16 As[3][128 * 32];  // 24 KB
  __shared__ __align__(16) u16 Bg[3][128 * 32];  // 24 KB
  __shared__ __align__(16) u16 Bu[3][128 * 32];  // 24 KB

  int tid = threadIdx.x;
  int w = tid >> 6, l = tid & 63;
  int wr = w >> 1, wc = w & 1;
  int lr = l & 15, g = l >> 4;

  const u16* asrc[2];
  int adst[2];
#pragma unroll
  for (int i = 0; i < 2; ++i) {
    int r = 32 * w + 16 * i + (l >> 2);
    unsigned grow = row0 + (unsigned)r;
    unsigned slot = base + (grow < n ? grow : 0);
    int chunk = (l & 3) ^ ((r >> 1) & 3);
    asrc[i] = xb + (size_t)slot_token[slot] * HDIM + 8 * chunk;
    adst[i] = (32 * w + 16 * i) * 32;
  }
  const u16* bgsrc[2];
  const u16* busrc[2];
  int bdst[2];
#pragma unroll
  for (int i = 0; i < 2; ++i) {
    int nn = 32 * w + 16 * i + (l >> 2);
    int chunk = (l & 3) ^ ((nn >> 1) & 3);
    size_t o = (size_t)e * HDIM * IDIM + (size_t)(col0 + nn) * HDIM + 8 * chunk;
    bgsrc[i] = wgT + o;
    busrc[i] = wuT + o;
    bdst[i] = (32 * w + 16 * i) * 32;
  }

  int afo[4], bfo[4];
#pragma unroll
  for (int mf = 0; mf < 4; ++mf) afo[mf] = rswz(wr * 64 + mf * 16 + lr, g);
#pragma unroll
  for (int nf = 0; nf < 4; ++nf) bfo[nf] = rswz(wc * 64 + nf * 16 + lr, g);

  f32x4 accg[4][4] = {};
  f32x4 accu[4][4] = {};

#define K4_STAGE(k0, buf)                           \
  do {                                              \
    gl_lds(asrc[0] + (k0), &As[buf][adst[0]]);      \
    gl_lds(asrc[1] + (k0), &As[buf][adst[1]]);      \
    gl_lds(bgsrc[0] + (k0), &Bg[buf][bdst[0]]);     \
    gl_lds(bgsrc[1] + (k0), &Bg[buf][bdst[1]]);     \
    gl_lds(busrc[0] + (k0), &Bu[buf][bdst[0]]);     \
    gl_lds(busrc[1] + (k0), &Bu[buf][bdst[1]]);     \
  } while (0)

  K4_STAGE(0, 0);
  K4_STAGE(32, 1);  // 12 loads in flight

  const int NK = HDIM / 32;
  int c = 0, sb = 2;
  for (int kt = 0; kt < NK; ++kt) {
    if (kt + 2 < NK) {
      K4_STAGE((kt + 2) * 32, sb);                       // 18 in flight
      asm volatile("s_waitcnt vmcnt(12)" ::: "memory");  // tile kt landed
    } else if (kt + 1 < NK) {
      asm volatile("s_waitcnt vmcnt(6)" ::: "memory");
    } else {
      asm volatile("s_waitcnt vmcnt(0)" ::: "memory");
    }
    __builtin_amdgcn_s_barrier();

    short8 af[4];
#pragma unroll
    for (int mf = 0; mf < 4; ++mf) af[mf] = *(const short8*)&As[c][afo[mf]];
#pragma unroll
    for (int nf = 0; nf < 4; ++nf) {
      short8 bgf = *(const short8*)&Bg[c][bfo[nf]];
      short8 buf = *(const short8*)&Bu[c][bfo[nf]];
#pragma unroll
      for (int mf = 0; mf < 4; ++mf) {
        accg[mf][nf] = __builtin_amdgcn_mfma_f32_16x16x32_bf16(af[mf], bgf, accg[mf][nf], 0, 0, 0);
        accu[mf][nf] = __builtin_amdgcn_mfma_f32_16x16x32_bf16(af[mf], buf, accu[mf][nf], 0, 0, 0);
      }
    }
    __builtin_amdgcn_s_barrier();
    c = (c == 2) ? 0 : c + 1;
    sb = (sb == 2) ? 0 : sb + 1;
  }
#undef K4_STAGE

  unsigned rows_left = n - row0;
#pragma unroll
  for (int mf = 0; mf < 4; ++mf)
#pragma unroll
    for (int nf = 0; nf < 4; ++nf)
#pragma unroll
      for (int j = 0; j < 4; ++j) {
        int rin = wr * 64 + mf * 16 + 4 * g + j;
        if ((unsigned)rin < rows_left) {
          size_t s = base + row0 + rin;
          int col = col0 + wc * 64 + nf * 16 + lr;
          float gg = accg[mf][nf][j];
          float uu = accu[mf][nf][j];
          float v = (gg / (1.f + expf(-gg))) * uu;
          act[s * IDIM + col] = f2bf(v);
        }
      }
}

// ---------------- K5: MFMA down -> bf16 y (R9/R13 structure) ----------------
__global__ __launch_bounds__(256, 2) void k5_down(
    const u16* __restrict__ act, const u16* __restrict__ wdT,
    const unsigned* __restrict__ cnt, u16* __restrict__ y) {
  int bx, by, e;
  xcd_decomp(bx, by, e);
  unsigned n = cnt[e];
  unsigned row0 = (unsigned)bx * 128;
  if (row0 >= n) return;
  unsigned base = prefix_base(cnt, e);
  int col0 = by * 256;

  __shared__ __align__(16) u16 As[3][128 * 32];  // 24 KB
  __shared__ __align__(16) u16 Bs[3][256 * 32];  // 48 KB

  int tid = threadIdx.x;
  int w = tid >> 6, l = tid & 63;
  int wr = w >> 1, wc = w & 1;
  int lr = l & 15, g = l >> 4;

  const u16* asrc[2];
  int adst[2];
#pragma unroll
  for (int i = 0; i < 2; ++i) {
    int r = 32 * w + 16 * i + (l >> 2);
    unsigned grow = row0 + (unsigned)r;
    unsigned slot = base + (grow < n ? grow : 0);
    int chunk = (l & 3) ^ ((r >> 1) & 3);
    asrc[i] = act + (size_t)slot * IDIM + 8 * chunk;
    adst[i] = (32 * w + 16 * i) * 32;
  }
  const u16* bsrc[4];
  int bdst[4];
#pragma unroll
  for (int i = 0; i < 4; ++i) {
    int nn = 64 * w + 16 * i + (l >> 2);
    int chunk = (l & 3) ^ ((nn >> 1) & 3);
    bsrc[i] = wdT + (size_t)e * IDIM * HDIM + (size_t)(col0 + nn) * IDIM + 8 * chunk;
    bdst[i] = (64 * w + 16 * i) * 32;
  }

  int afo[4], bfo[8];
#pragma unroll
  for (int mf = 0; mf < 4; ++mf) afo[mf] = rswz(wr * 64 + mf * 16 + lr, g);
#pragma unroll
  for (int nf = 0; nf < 8; ++nf) bfo[nf] = rswz(wc * 128 + nf * 16 + lr, g);

  f32x4 acc[4][8] = {};

#define K5_STAGE(k0, buf)                        \
  do {                                           \
    gl_lds(asrc[0] + (k0), &As[buf][adst[0]]);   \
    gl_lds(asrc[1] + (k0), &As[buf][adst[1]]);   \
    gl_lds(bsrc[0] + (k0), &Bs[buf][bdst[0]]);   \
    gl_lds(bsrc[1] + (k0), &Bs[buf][bdst[1]]);   \
    gl_lds(bsrc[2] + (k0), &Bs[buf][bdst[2]]);   \
    gl_lds(bsrc[3] + (k0), &Bs[buf][bdst[3]]);   \
  } while (0)

  K5_STAGE(0, 0);
  K5_STAGE(32, 1);

  const int NK = IDIM / 32;
  int c = 0, sb = 2;
  for (int kt = 0; kt < NK; ++kt) {
    if (kt + 2 < NK) {
      K5_STAGE((kt + 2) * 32, sb);
      asm volatile("s_waitcnt vmcnt(12)" ::: "memory");
    } else if (kt + 1 < NK) {
      asm volatile("s_waitcnt vmcnt(6)" ::: "memory");
    } else {
      asm volatile("s_waitcnt vmcnt(0)" ::: "memory");
    }
    __builtin_amdgcn_s_barrier();

    short8 af[4];
#pragma unroll
    for (int mf = 0; mf < 4; ++mf) af[mf] = *(const short8*)&As[c][afo[mf]];
#pragma unroll
    for (int nf = 0; nf < 8; ++nf) {
      short8 bd = *(const short8*)&Bs[c][bfo[nf]];
#pragma unroll
      for (int mf = 0; mf < 4; ++mf)
        acc[mf][nf] = __builtin_amdgcn_mfma_f32_16x16x32_bf16(af[mf], bd, acc[mf][nf], 0, 0, 0);
    }
    __builtin_amdgcn_s_barrier();
    c = (c == 2) ? 0 : c + 1;
    sb = (sb == 2) ? 0 : sb + 1;
  }
#undef K5_STAGE

  unsigned rows_left = n - row0;
#pragma unroll
  for (int mf = 0; mf < 4; ++mf)
#pragma unroll
    for (int j = 0; j < 4; ++j) {
      int rin = wr * 64 + mf * 16 + 4 * g + j;
      if ((unsigned)rin < rows_left) {
        size_t s = base + row0 + rin;
        u16* yrow = y + s * HDIM + col0 + wc * 128 + lr;
#pragma unroll
        for (int nf = 0; nf < 8; ++nf) yrow[nf * 16] = f2bf(acc[mf][nf][j]);
      }
    }
}

// ---------------- K6: combine out[t] = w0*y[s0] + w1*y[s1] ----------------
__global__ __launch_bounds__(512) void k6_combine(const u16* __restrict__ y,
                                                  const u16* __restrict__ tok2slot,
                                                  const float* __restrict__ slot_w,
                                                  float* __restrict__ out) {
  unsigned idx = blockIdx.x * 512 + threadIdx.x;  // one per 8 elems
  int t = idx >> 8;                               // HDIM/8 = 256 chunks per row
  int off = (idx & 255) * 8;
  int s0 = tok2slot[t * 2 + 0];
  int s1 = tok2slot[t * 2 + 1];
  float w0 = slot_w[s0];
  float w1 = slot_w[s1];
  short8 a = *(const short8*)(y + (size_t)s0 * HDIM + off);
  short8 b = *(const short8*)(y + (size_t)s1 * HDIM + off);
  float* o = out + (size_t)t * HDIM + off;
  float4 o0, o1;
  o0.x = w0 * bf2f((u16)a[0]) + w1 * bf2f((u16)b[0]);
  o0.y = w0 * bf2f((u16)a[1]) + w1 * bf2f((u16)b[1]);
  o0.z = w0 * bf2f((u16)a[2]) + w1 * bf2f((u16)b[2]);
  o0.w = w0 * bf2f((u16)a[3]) + w1 * bf2f((u16)b[3]);
  o1.x = w0 * bf2f((u16)a[4]) + w1 * bf2f((u16)b[4]);
  o1.y = w0 * bf2f((u16)a[5]) + w1 * bf2f((u16)b[5]);
  o1.z = w0 * bf2f((u16)a[6]) + w1 * bf2f((u16)b[6]);
  o1.w = w0 * bf2f((u16)a[7]) + w1 * bf2f((u16)b[7]);
  *(float4*)o = o0;
  *(float4*)(o + 4) = o1;
}

extern "C" void kernel_launch(void* const* d_in, const int* in_sizes, int n_in,
                              void* d_out, int out_size, void* d_ws, size_t ws_size,
                              hipStream_t stream) {
  const float* x = (const float*)d_in[0];
  const float* wgate = (const float*)d_in[1];
  const float* wg = (const float*)d_in[2];
  const float* wu = (const float*)d_in[3];
  const float* wd = (const float*)d_in[4];
  float* out = (float*)d_out;
  float* logits = out + (size_t)T_TOK * HDIM;

  const size_t XBF_OFF = 132096;
  const size_t ACT_OFF = XBF_OFF + (size_t)T_TOK * HDIM * 2;
  const size_t WGT_OFF = ACT_OFF + (size_t)2 * T_TOK * IDIM * 2;
  const size_t WUT_OFF = WGT_OFF + (size_t)NE * HDIM * IDIM * 2;
  const size_t WDT_OFF = WUT_OFF + (size_t)NE * HDIM * IDIM * 2;
  const size_t NEED_T3 = WDT_OFF + (size_t)NE * IDIM * HDIM * 2;  // 167,904,256 (proven R5)
  if (ws_size < NEED_T3) return;  // loud failure

  char* ws = (char*)d_ws;
  unsigned* meta = (unsigned*)ws;
  unsigned* cnt = meta + 0;
  unsigned* cursor = meta + 8;
  u16* slot_token = (u16*)(ws + 256);
  float* slot_w = (float*)(ws + 33024);
  u16* tok2slot = (u16*)(ws + 98560);
  u16* xbf = (u16*)(ws + XBF_OFF);
  u16* act = (u16*)(ws + ACT_OFF);
  u16* wgT = (u16*)(ws + WGT_OFF);
  u16* wuT = (u16*)(ws + WUT_OFF);
  u16* wdT = (u16*)(ws + WDT_OFF);
  u16* y = (u16*)(ws + WGT_OFF);  // reuses wgT+wuT (dead after k4)
  char* sel = (char*)act;         // dead before k4 writes act
  float* wt = (float*)((char*)act + 16384);

  hipMemsetAsync(meta, 0, 64, stream);  // cnt[8] + cursor[8]
  k01t_fused<<<T_TOK / 4 + 2048, 256, 0, stream>>>(x, wgate, xbf, logits, sel, wt, wg, wgT, wu,
                                                   wuT, wd, wdT);
  k2_count<<<T_TOK * 2 / (256 * 8), 256, 0, stream>>>(sel, cnt);
  k3_assign<<<T_TOK / 256, 256, 0, stream>>>(sel, wt, cnt, cursor, slot_token, slot_w, tok2slot);
  k4_gateup<<<dim3(T_TOK / 128, IDIM / 128, NE), 256, 0, stream>>>(xbf, wgT, wuT, slot_token,
                                                                   cnt, act);
  k5_down<<<dim3(T_TOK / 128, HDIM / 256, NE), 256, 0, stream>>>(act, wdT, cnt, y);
  k6_combine<<<T_TOK * HDIM / 8 / 512, 512, 0, stream>>>(y, tok2slot, slot_w, out);
}